// Round 1
// baseline (1127.997 us; speedup 1.0000x reference)
//
#include <hip/hip_runtime.h>
#include <math.h>

#define D_MODEL 1024
#define NHEAD 16
#define HEAD_DIM 64
#define MAX_REL 512
#define BATCH 2
#define SEQ 2048
#define KDIM 1024
#define BHSTRIDE (SEQ * HEAD_DIM)  // 131072

// ---------------------------------------------------------------------------
// GEMM: C[m][n] = sum_k A[m][k] * W[n][k] + bias[n]
// 128x128 tile, BK=16, 256 threads, 8x8 micro-tile per thread.
// EPI=0: plain row-major output [M][N] (N = gridDim.x*128)
// EPI=1: scatter to qkv workspace [which][b][h][l][dh]
// ---------------------------------------------------------------------------
template <int EPI>
__global__ __launch_bounds__(256) void gemm_xwt(
    const float* __restrict__ A, const float* __restrict__ W,
    const float* __restrict__ bias, float* __restrict__ out)
{
    __shared__ __align__(16) float As[16][132];
    __shared__ __align__(16) float Bs[16][132];

    const int tid = threadIdx.x;
    const int tx = tid & 15, ty = tid >> 4;
    const int m0 = blockIdx.y * 128, n0 = blockIdx.x * 128;
    const int N = gridDim.x * 128;

    float acc[8][8];
#pragma unroll
    for (int i = 0; i < 8; ++i)
#pragma unroll
        for (int j = 0; j < 8; ++j) acc[i][j] = 0.f;

    for (int k0 = 0; k0 < KDIM; k0 += 16) {
#pragma unroll
        for (int u = 0; u < 2; ++u) {
            int f = tid * 2 + u;          // 0..511
            int row = f >> 2, c4 = f & 3; // row 0..127, c4 0..3
            float4 av = *(const float4*)&A[(size_t)(m0 + row) * KDIM + k0 + c4 * 4];
            float4 wv = *(const float4*)&W[(size_t)(n0 + row) * KDIM + k0 + c4 * 4];
            As[c4 * 4 + 0][row] = av.x; As[c4 * 4 + 1][row] = av.y;
            As[c4 * 4 + 2][row] = av.z; As[c4 * 4 + 3][row] = av.w;
            Bs[c4 * 4 + 0][row] = wv.x; Bs[c4 * 4 + 1][row] = wv.y;
            Bs[c4 * 4 + 2][row] = wv.z; Bs[c4 * 4 + 3][row] = wv.w;
        }
        __syncthreads();
#pragma unroll
        for (int kk = 0; kk < 16; ++kk) {
            float a[8], b[8];
            *(float4*)&a[0] = *(const float4*)&As[kk][ty * 8];
            *(float4*)&a[4] = *(const float4*)&As[kk][ty * 8 + 4];
            *(float4*)&b[0] = *(const float4*)&Bs[kk][tx * 8];
            *(float4*)&b[4] = *(const float4*)&Bs[kk][tx * 8 + 4];
#pragma unroll
            for (int i = 0; i < 8; ++i)
#pragma unroll
                for (int j = 0; j < 8; ++j) acc[i][j] = fmaf(a[i], b[j], acc[i][j]);
        }
        __syncthreads();
    }

    if (EPI == 0) {
#pragma unroll
        for (int i = 0; i < 8; ++i) {
            int m = m0 + ty * 8 + i;
#pragma unroll
            for (int j4 = 0; j4 < 2; ++j4) {
                int n = n0 + tx * 8 + j4 * 4;
                float4 v;
                v.x = acc[i][j4 * 4 + 0] + bias[n + 0];
                v.y = acc[i][j4 * 4 + 1] + bias[n + 1];
                v.z = acc[i][j4 * 4 + 2] + bias[n + 2];
                v.w = acc[i][j4 * 4 + 3] + bias[n + 3];
                *(float4*)&out[(size_t)m * N + n] = v;
            }
        }
    } else {
#pragma unroll
        for (int i = 0; i < 8; ++i) {
            int m = m0 + ty * 8 + i;
            int bq = m >> 11, l = m & 2047;
#pragma unroll
            for (int j = 0; j < 8; ++j) {
                int n = n0 + tx * 8 + j;
                float val = acc[i][j] + bias[n];
                int which = n >> 10;
                int rem = n & 1023;
                int hh = rem >> 6;
                int dh = rem & 63;
                out[((size_t)(which * 2 + bq) * 16 + hh) * BHSTRIDE + (size_t)l * 64 + dh] = val;
            }
        }
    }
}

// ---------------------------------------------------------------------------
// Flash-style fp32 attention. One WG (256 thr) = 64 q-rows of one (b,h).
// K-tile/V-tile of 64 rows, online softmax, P staged in LDS for the PV step.
// Thread tile: 4 rows x 4 cols (ty=row group, tx=col group).
// ---------------------------------------------------------------------------
__global__ __launch_bounds__(256) void attn_kernel(
    const float* __restrict__ qkv, const float* __restrict__ rel_emb,
    float* __restrict__ attn2)
{
    __shared__ __align__(16) float Qs[64][68];
    __shared__ __align__(16) float Kst[64][68]; // [d][kc]
    __shared__ __align__(16) float Vs[64][68];  // [kc][d]
    __shared__ __align__(16) float Ps[64][68];
    __shared__ __align__(16) float Rel[1026];

    const int b = blockIdx.z, h = blockIdx.y;
    const int q0 = blockIdx.x * 64;
    const int tid = threadIdx.x;
    const int tx = tid & 15, ty = tid >> 4;
    const int r0 = ty * 4, c0 = tx * 4;

    const float* qb = qkv + ((size_t)(0 + b) * 16 + h) * BHSTRIDE;
    const float* kb = qkv + ((size_t)(2 + b) * 16 + h) * BHSTRIDE;
    const float* vb = qkv + ((size_t)(4 + b) * 16 + h) * BHSTRIDE;

    // Load Q tile (64x64) and the rel-emb column for this head
    for (int f = tid; f < 1024; f += 256) {
        int row = f >> 4, c4 = f & 15;
        *(float4*)&Qs[row][c4 * 4] = *(const float4*)&qb[(size_t)(q0 + row) * 64 + c4 * 4];
    }
    for (int i = tid; i < 2 * MAX_REL + 1; i += 256) Rel[i] = rel_emb[i * NHEAD + h];

    float m_run[4], l_run[4], o[4][4];
#pragma unroll
    for (int i = 0; i < 4; ++i) {
        m_run[i] = -INFINITY;
        l_run[i] = 0.f;
#pragma unroll
        for (int j = 0; j < 4; ++j) o[i][j] = 0.f;
    }
    __syncthreads();

    for (int kt = 0; kt < SEQ / 64; ++kt) {
        const int k0 = kt * 64;
        // Load K (transposed: Kst[d][kc]) and V (natural) tiles
        for (int f = tid; f < 1024; f += 256) {
            int row = f >> 4, c4 = f & 15;
            float4 kv = *(const float4*)&kb[(size_t)(k0 + row) * 64 + c4 * 4];
            Kst[c4 * 4 + 0][row] = kv.x; Kst[c4 * 4 + 1][row] = kv.y;
            Kst[c4 * 4 + 2][row] = kv.z; Kst[c4 * 4 + 3][row] = kv.w;
            *(float4*)&Vs[row][c4 * 4] = *(const float4*)&vb[(size_t)(k0 + row) * 64 + c4 * 4];
        }
        __syncthreads();

        // S = Q K^T  (4x4 per thread)
        float s[4][4];
#pragma unroll
        for (int i = 0; i < 4; ++i)
#pragma unroll
            for (int j = 0; j < 4; ++j) s[i][j] = 0.f;
#pragma unroll
        for (int d4 = 0; d4 < 16; ++d4) {
            float4 qv[4], kv[4];
#pragma unroll
            for (int i = 0; i < 4; ++i) qv[i] = *(const float4*)&Qs[r0 + i][d4 * 4];
#pragma unroll
            for (int dd = 0; dd < 4; ++dd) kv[dd] = *(const float4*)&Kst[d4 * 4 + dd][c0];
#pragma unroll
            for (int dd = 0; dd < 4; ++dd) {
                const float* qp = (const float*)&qv[0];
#pragma unroll
                for (int i = 0; i < 4; ++i) {
                    float qe = ((const float*)&qv[i])[dd];
#pragma unroll
                    for (int j = 0; j < 4; ++j)
                        s[i][j] = fmaf(qe, ((const float*)&kv[dd])[j], s[i][j]);
                }
                (void)qp;
            }
        }

        // scale + rel-pos bias, then online softmax update
#pragma unroll
        for (int i = 0; i < 4; ++i) {
            int qg = q0 + r0 + i;
#pragma unroll
            for (int j = 0; j < 4; ++j) {
                int kg = k0 + c0 + j;
                int rel = kg - qg;
                rel = rel < -MAX_REL ? -MAX_REL : (rel > MAX_REL ? MAX_REL : rel);
                s[i][j] = fmaf(s[i][j], 0.125f, Rel[rel + MAX_REL]);
            }
        }

#pragma unroll
        for (int i = 0; i < 4; ++i) {
            float mloc = fmaxf(fmaxf(s[i][0], s[i][1]), fmaxf(s[i][2], s[i][3]));
#pragma unroll
            for (int off = 1; off < 16; off <<= 1)
                mloc = fmaxf(mloc, __shfl_xor(mloc, off, 64));
            float mnew = fmaxf(m_run[i], mloc);
            float scale = __expf(m_run[i] - mnew);
            float p[4], psum = 0.f;
#pragma unroll
            for (int j = 0; j < 4; ++j) {
                p[j] = __expf(s[i][j] - mnew);
                psum += p[j];
            }
#pragma unroll
            for (int off = 1; off < 16; off <<= 1)
                psum += __shfl_xor(psum, off, 64);
            l_run[i] = l_run[i] * scale + psum;
            m_run[i] = mnew;
#pragma unroll
            for (int j = 0; j < 4; ++j) o[i][j] *= scale;
            float4 pv = make_float4(p[0], p[1], p[2], p[3]);
            *(float4*)&Ps[r0 + i][c0] = pv;
        }
        __syncthreads();

        // O += P V  (4x4 per thread)
#pragma unroll
        for (int kc4 = 0; kc4 < 16; ++kc4) {
            float4 pv[4], vv[4];
#pragma unroll
            for (int i = 0; i < 4; ++i) pv[i] = *(const float4*)&Ps[r0 + i][kc4 * 4];
#pragma unroll
            for (int dd = 0; dd < 4; ++dd) vv[dd] = *(const float4*)&Vs[kc4 * 4 + dd][c0];
#pragma unroll
            for (int dd = 0; dd < 4; ++dd)
#pragma unroll
                for (int i = 0; i < 4; ++i) {
                    float pe = ((const float*)&pv[i])[dd];
#pragma unroll
                    for (int j = 0; j < 4; ++j)
                        o[i][j] = fmaf(pe, ((const float*)&vv[dd])[j], o[i][j]);
                }
        }
        __syncthreads();
    }

    // finalize and write [B][L][D] with col = h*64 + c0 + j
#pragma unroll
    for (int i = 0; i < 4; ++i) {
        float inv = 1.f / l_run[i];
        float4 v = make_float4(o[i][0] * inv, o[i][1] * inv, o[i][2] * inv, o[i][3] * inv);
        size_t row = (size_t)b * SEQ + q0 + r0 + i;
        *(float4*)&attn2[row * D_MODEL + h * 64 + c0] = v;
    }
}

// ---------------------------------------------------------------------------
extern "C" void kernel_launch(void* const* d_in, const int* in_sizes, int n_in,
                              void* d_out, int out_size, void* d_ws, size_t ws_size,
                              hipStream_t stream)
{
    (void)in_sizes; (void)n_in; (void)out_size; (void)ws_size;
    const float* x       = (const float*)d_in[0];
    const float* qkv_w   = (const float*)d_in[1];
    const float* qkv_b   = (const float*)d_in[2];
    const float* out_w   = (const float*)d_in[3];
    const float* out_b   = (const float*)d_in[4];
    const float* rel_emb = (const float*)d_in[5];
    float* out = (float*)d_out;

    float* qkv_ws = (float*)d_ws;                                   // 3*2*16*2048*64 floats
    float* attn2  = qkv_ws + (size_t)3 * BATCH * NHEAD * BHSTRIDE;  // 4096*1024 floats

    // 1) QKV projection, scatter to [which][b][h][l][dh]
    gemm_xwt<1><<<dim3(24, 32), 256, 0, stream>>>(x, qkv_w, qkv_b, qkv_ws);
    // 2) attention -> attn2 [B][L][D]
    attn_kernel<<<dim3(SEQ / 64, NHEAD, BATCH), 256, 0, stream>>>(qkv_ws, rel_emb, attn2);
    // 3) output projection
    gemm_xwt<0><<<dim3(8, 32), 256, 0, stream>>>(attn2, out_w, out_b, out);
}

// Round 3
// 499.450 us; speedup vs baseline: 2.2585x; 2.2585x over previous
//
#include <hip/hip_runtime.h>
#include <math.h>

#define D_MODEL 1024
#define NHEAD 16
#define HEAD_DIM 64
#define MAX_REL 512
#define BATCH 2
#define SEQ 2048
#define KDIM 1024

typedef __attribute__((ext_vector_type(8))) short bf16x8;
typedef __attribute__((ext_vector_type(4))) float f32x4;

__device__ __forceinline__ unsigned short f2bf(float f) {
    unsigned int u = __float_as_uint(f);
    u += 0x7fff + ((u >> 16) & 1);   // RNE
    return (unsigned short)(u >> 16);
}
__device__ __forceinline__ float bf2f(unsigned short h) {
    return __uint_as_float(((unsigned int)h) << 16);
}
__device__ __forceinline__ void gload_lds16(const void* g, void* l) {
    __builtin_amdgcn_global_load_lds(
        (const __attribute__((address_space(1))) void*)g,
        (__attribute__((address_space(3))) void*)l, 16, 0, 0);
}

// ---------------------------------------------------------------------------
// split fp32 -> (hi, lo) bf16
// ---------------------------------------------------------------------------
__global__ __launch_bounds__(256) void split_bf16(
    const float* __restrict__ in, unsigned short* __restrict__ hi,
    unsigned short* __restrict__ lo, int n4)
{
    int i = blockIdx.x * 256 + threadIdx.x;
    if (i >= n4) return;
    float4 v = ((const float4*)in)[i];
    float vv[4] = {v.x, v.y, v.z, v.w};
    unsigned short hh[4], ll[4];
#pragma unroll
    for (int j = 0; j < 4; ++j) {
        hh[j] = f2bf(vv[j]);
        ll[j] = f2bf(vv[j] - bf2f(hh[j]));
    }
    ((ushort4*)hi)[i] = make_ushort4(hh[0], hh[1], hh[2], hh[3]);
    ((ushort4*)lo)[i] = make_ushort4(ll[0], ll[1], ll[2], ll[3]);
}

// ---------------------------------------------------------------------------
// Split-bf16 MFMA GEMM: C[m][n] = sum_k A[m][k]*W[n][k] + bias[n]
// 128x128 tile, BK=64, 256 thr (4 waves, 2x2), 16x16x32 bf16 MFMA.
// 3 passes: Ahi*Whi + Ahi*Wlo + Alo*Whi.
// EPI==1: QKV scatter (Q fp32, K hi/lo bf16, V transposed bf16)
// EPI==2: plain fp32 out [M][1024]
// ---------------------------------------------------------------------------
template <int EPI>
__global__ __launch_bounds__(256) void gemm_split(
    const unsigned short* __restrict__ Ahi, const unsigned short* __restrict__ Alo,
    const unsigned short* __restrict__ Whi, const unsigned short* __restrict__ Wlo,
    const float* __restrict__ bias,
    float* __restrict__ outf,
    unsigned short* __restrict__ khi, unsigned short* __restrict__ klo,
    unsigned short* __restrict__ vt)
{
    __shared__ __align__(16) unsigned short As[128 * 64];
    __shared__ __align__(16) unsigned short Bs[128 * 64];
    const int K = KDIM;
    const int tid = threadIdx.x;
    const int wid = tid >> 6, lane = tid & 63;
    const int l15 = lane & 15, g = lane >> 4;
    const int m0 = blockIdx.y * 128, n0 = blockIdx.x * 128;
    const int wr = wid >> 1, wc = wid & 1;

    const f32x4 fzero = {0.f, 0.f, 0.f, 0.f};
    f32x4 acc[4][4];
#pragma unroll
    for (int i = 0; i < 4; ++i)
#pragma unroll
        for (int j = 0; j < 4; ++j) acc[i][j] = fzero;

    const unsigned short* APs[3] = {Ahi, Ahi, Alo};
    const unsigned short* WPs[3] = {Whi, Wlo, Whi};

    for (int p = 0; p < 3; ++p) {
        const unsigned short* Ap = APs[p] + (size_t)m0 * K;
        const unsigned short* Wp = WPs[p] + (size_t)n0 * K;
        for (int k0 = 0; k0 < K; k0 += 64) {
#pragma unroll
            for (int u = 0; u < 4; ++u) {
                int bo = wid * 4096 + u * 1024 + lane * 16;   // byte in 16KB tile
                int row = bo >> 7, col = (bo & 127) >> 1;
                int ub = (wid * 4096 + u * 1024) >> 1;         // wave-uniform elem base
                gload_lds16(Ap + (size_t)row * K + k0 + col, &As[ub]);
                gload_lds16(Wp + (size_t)row * K + k0 + col, &Bs[ub]);
            }
            __syncthreads();
#pragma unroll
            for (int kc = 0; kc < 2; ++kc) {
                bf16x8 af[4], bfr[4];
#pragma unroll
                for (int i = 0; i < 4; ++i)
                    af[i] = *(const bf16x8*)&As[(wr * 64 + i * 16 + l15) * 64 + kc * 32 + g * 8];
#pragma unroll
                for (int j = 0; j < 4; ++j)
                    bfr[j] = *(const bf16x8*)&Bs[(wc * 64 + j * 16 + l15) * 64 + kc * 32 + g * 8];
#pragma unroll
                for (int i = 0; i < 4; ++i)
#pragma unroll
                    for (int j = 0; j < 4; ++j)
                        acc[i][j] = __builtin_amdgcn_mfma_f32_16x16x32_bf16(af[i], bfr[j], acc[i][j], 0, 0, 0);
            }
            __syncthreads();
        }
    }

#pragma unroll
    for (int i = 0; i < 4; ++i) {
        int mbase = m0 + wr * 64 + i * 16 + g * 4;
#pragma unroll
        for (int j = 0; j < 4; ++j) {
            int n = n0 + wc * 64 + j * 16 + l15;
            float bv = bias[n];
            if (EPI == 2) {
#pragma unroll
                for (int r = 0; r < 4; ++r)
                    outf[(size_t)(mbase + r) * 1024 + n] = acc[i][j][r] + bv;
            } else {
                int which = n >> 10, rem = n & 1023, h = rem >> 6, d = rem & 63;
#pragma unroll
                for (int r = 0; r < 4; ++r) {
                    int mm = mbase + r;
                    int bb = mm >> 11, ll = mm & 2047;
                    size_t bh = (size_t)(bb * 16 + h);
                    float val = acc[i][j][r] + bv;
                    if (which == 0) {
                        outf[(bh * 2048 + ll) * 64 + d] = val;
                    } else if (which == 1) {
                        unsigned short hh = f2bf(val);
                        size_t idx = (bh * 2048 + ll) * 64 + d;
                        khi[idx] = hh;
                        klo[idx] = f2bf(val - bf2f(hh));
                    } else {
                        vt[(bh * 64 + d) * 2048 + ll] = f2bf(val);
                    }
                }
            }
        }
    }
}

// ---------------------------------------------------------------------------
// Flash attention, MFMA. 4 waves x 16 q-rows (QB=64), KV-tile 64.
// QK^T: split-bf16 (3 passes). Softmax: 16-lane shuffle online. PV: bf16.
// ---------------------------------------------------------------------------
__global__ __launch_bounds__(256) void attn_mfma(
    const float* __restrict__ qws, const unsigned short* __restrict__ khi,
    const unsigned short* __restrict__ klo, const unsigned short* __restrict__ vt,
    const float* __restrict__ rel_emb,
    unsigned short* __restrict__ ohi, unsigned short* __restrict__ olo)
{
    __shared__ __align__(16) unsigned short Khi_s[64 * 64];
    __shared__ __align__(16) unsigned short Klo_s[64 * 64];
    __shared__ __align__(16) unsigned short Vt_s[64 * 64];
    __shared__ __align__(16) unsigned short Ps[64 * 64];
    __shared__ float Rel[2 * MAX_REL + 1];

    // XCD-aware swizzle: 1024 WGs = 8 XCDs x 128; same (b,h) stays on one XCD.
    int flat = blockIdx.x + 32 * (blockIdx.y + 16 * blockIdx.z);
    int swz = (flat & 7) * 128 + (flat >> 3);
    int qb = swz & 31, h = (swz >> 5) & 15, b = swz >> 9;
    int q0 = qb * 64;

    const int tid = threadIdx.x;
    const int wid = tid >> 6, lane = tid & 63;
    const int l15 = lane & 15, g = lane >> 4;
    size_t bh = (size_t)(b * 16 + h);
    const float* qb_p = qws + bh * SEQ * 64;
    const unsigned short* kbh = khi + bh * SEQ * 64;
    const unsigned short* kbl = klo + bh * SEQ * 64;
    const unsigned short* vbt = vt + bh * 64 * SEQ;

    for (int i = tid; i < 2 * MAX_REL + 1; i += 256) Rel[i] = rel_emb[i * NHEAD + h];

    // Q fragments (hi/lo) in registers
    bf16x8 qhi[2], qlo[2];
    int qrow = q0 + wid * 16 + l15;
#pragma unroll
    for (int kc = 0; kc < 2; ++kc) {
        float4 f0 = *(const float4*)&qb_p[(size_t)qrow * 64 + kc * 32 + g * 8];
        float4 f1 = *(const float4*)&qb_p[(size_t)qrow * 64 + kc * 32 + g * 8 + 4];
        float ff[8] = {f0.x, f0.y, f0.z, f0.w, f1.x, f1.y, f1.z, f1.w};
#pragma unroll
        for (int j = 0; j < 8; ++j) {
            unsigned short hh = f2bf(ff[j]);
            qhi[kc][j] = (short)hh;
            qlo[kc][j] = (short)f2bf(ff[j] - bf2f(hh));
        }
    }

    const f32x4 fzero = {0.f, 0.f, 0.f, 0.f};
    f32x4 o[4];
    float m_run[4], l_run[4];
#pragma unroll
    for (int r = 0; r < 4; ++r) { m_run[r] = -1e30f; l_run[r] = 0.f; }
#pragma unroll
    for (int df = 0; df < 4; ++df) o[df] = fzero;

    for (int kt = 0; kt < SEQ / 64; ++kt) {
        int k0 = kt * 64;
        // stage K(hi,lo) and V^T tiles (bf16, linear LDS)
#pragma unroll
        for (int u = 0; u < 2; ++u) {
            int bo = wid * 2048 + u * 1024 + lane * 16;
            int row = bo >> 7, col = (bo & 127) >> 1;
            int ub = (wid * 2048 + u * 1024) >> 1;
            gload_lds16(kbh + (size_t)(k0 + row) * 64 + col, &Khi_s[ub]);
            gload_lds16(kbl + (size_t)(k0 + row) * 64 + col, &Klo_s[ub]);
            gload_lds16(vbt + (size_t)row * SEQ + k0 + col, &Vt_s[ub]);
        }
        __syncthreads();

        // S = Q K^T (split, 3 passes)
        f32x4 s[4];
#pragma unroll
        for (int cf = 0; cf < 4; ++cf) {
            s[cf] = fzero;
#pragma unroll
            for (int kc = 0; kc < 2; ++kc) {
                bf16x8 kh = *(const bf16x8*)&Khi_s[(cf * 16 + l15) * 64 + kc * 32 + g * 8];
                bf16x8 kl = *(const bf16x8*)&Klo_s[(cf * 16 + l15) * 64 + kc * 32 + g * 8];
                s[cf] = __builtin_amdgcn_mfma_f32_16x16x32_bf16(qhi[kc], kh, s[cf], 0, 0, 0);
                s[cf] = __builtin_amdgcn_mfma_f32_16x16x32_bf16(qlo[kc], kh, s[cf], 0, 0, 0);
                s[cf] = __builtin_amdgcn_mfma_f32_16x16x32_bf16(qhi[kc], kl, s[cf], 0, 0, 0);
            }
        }

        // scale + rel-pos bias
        int qg = q0 + wid * 16 + g * 4;
#pragma unroll
        for (int cf = 0; cf < 4; ++cf) {
            int kg = k0 + cf * 16 + l15;
#pragma unroll
            for (int r = 0; r < 4; ++r) {
                int rel = kg - (qg + r);
                rel = rel < -MAX_REL ? -MAX_REL : (rel > MAX_REL ? MAX_REL : rel);
                s[cf][r] = fmaf(s[cf][r], 0.125f, Rel[rel + MAX_REL]);
            }
        }

        // online softmax: row = reg r, reduce over 16-lane key groups
#pragma unroll
        for (int r = 0; r < 4; ++r) {
            float mloc = fmaxf(fmaxf(s[0][r], s[1][r]), fmaxf(s[2][r], s[3][r]));
#pragma unroll
            for (int off = 1; off < 16; off <<= 1)
                mloc = fmaxf(mloc, __shfl_xor(mloc, off, 64));
            float mnew = fmaxf(m_run[r], mloc);
            float sc = __expf(m_run[r] - mnew);
            m_run[r] = mnew;
            float psum = 0.f;
#pragma unroll
            for (int cf = 0; cf < 4; ++cf) {
                float p = __expf(s[cf][r] - mnew);
                s[cf][r] = p;
                psum += p;
            }
#pragma unroll
            for (int off = 1; off < 16; off <<= 1)
                psum += __shfl_xor(psum, off, 64);
            l_run[r] = l_run[r] * sc + psum;
#pragma unroll
            for (int df = 0; df < 4; ++df) o[df][r] = o[df][r] * sc;  // row r only
        }

        // P -> LDS (bf16), own-wave strip (no barrier needed: own-wave RAW)
#pragma unroll
        for (int cf = 0; cf < 4; ++cf)
#pragma unroll
            for (int r = 0; r < 4; ++r)
                Ps[(wid * 16 + g * 4 + r) * 64 + cf * 16 + l15] = f2bf(s[cf][r]);

        // O += P V
#pragma unroll
        for (int kc = 0; kc < 2; ++kc) {
            bf16x8 pa = *(const bf16x8*)&Ps[(wid * 16 + l15) * 64 + kc * 32 + g * 8];
#pragma unroll
            for (int df = 0; df < 4; ++df) {
                bf16x8 vb = *(const bf16x8*)&Vt_s[(df * 16 + l15) * 64 + kc * 32 + g * 8];
                o[df] = __builtin_amdgcn_mfma_f32_16x16x32_bf16(pa, vb, o[df], 0, 0, 0);
            }
        }
        __syncthreads();
    }

    // epilogue: normalize, split-write attn2 (hi, lo)
#pragma unroll
    for (int r = 0; r < 4; ++r) {
        float inv = 1.f / l_run[r];
        size_t row = (size_t)b * SEQ + q0 + wid * 16 + g * 4 + r;
#pragma unroll
        for (int df = 0; df < 4; ++df) {
            float val = o[df][r] * inv;
            unsigned short hh = f2bf(val);
            size_t idx = row * D_MODEL + h * 64 + df * 16 + l15;
            ohi[idx] = hh;
            olo[idx] = f2bf(val - bf2f(hh));
        }
    }
}

// ---------------------------------------------------------------------------
extern "C" void kernel_launch(void* const* d_in, const int* in_sizes, int n_in,
                              void* d_out, int out_size, void* d_ws, size_t ws_size,
                              hipStream_t stream)
{
    (void)in_sizes; (void)n_in; (void)out_size; (void)ws_size;
    const float* x       = (const float*)d_in[0];
    const float* qkv_w   = (const float*)d_in[1];
    const float* qkv_b   = (const float*)d_in[2];
    const float* out_w   = (const float*)d_in[3];
    const float* out_b   = (const float*)d_in[4];
    const float* rel_emb = (const float*)d_in[5];
    float* out = (float*)d_out;

    char* ws = (char*)d_ws;
    float*          qws  = (float*)(ws + 0);                    // 16 MB fp32 Q [b][h][l][d]
    unsigned short* khi  = (unsigned short*)(ws + 16777216);    // 8 MB
    unsigned short* klo  = (unsigned short*)(ws + 25165824);    // 8 MB
    unsigned short* vt   = (unsigned short*)(ws + 33554432);    // 8 MB [b][h][d][l]
    unsigned short* xhi  = (unsigned short*)(ws + 41943040);    // 8 MB (aliases attn2hi)
    unsigned short* xlo  = (unsigned short*)(ws + 50331648);    // 8 MB (aliases attn2lo)
    unsigned short* wqhi = (unsigned short*)(ws + 58720256);    // 6 MB
    unsigned short* wqlo = (unsigned short*)(ws + 65011712);    // 6 MB
    unsigned short* owhi = (unsigned short*)(ws + 71303168);    // 2 MB
    unsigned short* owlo = (unsigned short*)(ws + 73400320);    // 2 MB
    unsigned short* a2hi = xhi;   // attn2 split reuses x-split region
    unsigned short* a2lo = xlo;

    // 1) splits
    split_bf16<<<4096, 256, 0, stream>>>(x, xhi, xlo, 1048576);
    split_bf16<<<3072, 256, 0, stream>>>(qkv_w, wqhi, wqlo, 786432);
    split_bf16<<<1024, 256, 0, stream>>>(out_w, owhi, owlo, 262144);
    // 2) QKV projection (scatter epilogue)
    gemm_split<1><<<dim3(24, 32), 256, 0, stream>>>(xhi, xlo, wqhi, wqlo, qkv_b,
                                                    qws, khi, klo, vt);
    // 3) attention
    attn_mfma<<<dim3(32, 16, 2), 256, 0, stream>>>(qws, khi, klo, vt, rel_emb, a2hi, a2lo);
    // 4) out projection
    gemm_split<2><<<dim3(8, 32), 256, 0, stream>>>(a2hi, a2lo, owhi, owlo, out_b,
                                                   out, nullptr, nullptr, nullptr);
}

// Round 4
// 459.160 us; speedup vs baseline: 2.4567x; 1.0877x over previous
//
#include <hip/hip_runtime.h>
#include <math.h>

#define D_MODEL 1024
#define NHEAD 16
#define HEAD_DIM 64
#define MAX_REL 512
#define BATCH 2
#define SEQ 2048
#define KDIM 1024

typedef __attribute__((ext_vector_type(8))) short bf16x8;
typedef __attribute__((ext_vector_type(4))) float f32x4;

__device__ __forceinline__ unsigned short f2bf(float f) {
    unsigned int u = __float_as_uint(f);
    u += 0x7fff + ((u >> 16) & 1);   // RNE
    return (unsigned short)(u >> 16);
}
__device__ __forceinline__ float bf2f(unsigned short h) {
    return __uint_as_float(((unsigned int)h) << 16);
}
__device__ __forceinline__ void gload_lds16(const void* g, void* l) {
    __builtin_amdgcn_global_load_lds(
        (const __attribute__((address_space(1))) void*)g,
        (__attribute__((address_space(3))) void*)l, 16, 0, 0);
}

// ---------------------------------------------------------------------------
// split fp32 -> (hi, lo) bf16
// ---------------------------------------------------------------------------
__global__ __launch_bounds__(256) void split_bf16(
    const float* __restrict__ in, unsigned short* __restrict__ hi,
    unsigned short* __restrict__ lo, int n4)
{
    int i = blockIdx.x * 256 + threadIdx.x;
    if (i >= n4) return;
    float4 v = ((const float4*)in)[i];
    float vv[4] = {v.x, v.y, v.z, v.w};
    unsigned short hh[4], ll[4];
#pragma unroll
    for (int j = 0; j < 4; ++j) {
        hh[j] = f2bf(vv[j]);
        ll[j] = f2bf(vv[j] - bf2f(hh[j]));
    }
    ((ushort4*)hi)[i] = make_ushort4(hh[0], hh[1], hh[2], hh[3]);
    ((ushort4*)lo)[i] = make_ushort4(ll[0], ll[1], ll[2], ll[3]);
}

// ---------------------------------------------------------------------------
// Split-bf16 MFMA GEMM: C[m][n] = sum_k A[m][k]*W[n][k] + bias[n]
// 128x128 tile, BK=64, 256 thr (4 waves, 2x2), 16x16x32 bf16 MFMA.
// 3 passes: Ahi*Whi + Ahi*Wlo + Alo*Whi.   (unchanged this round)
// ---------------------------------------------------------------------------
template <int EPI>
__global__ __launch_bounds__(256) void gemm_split(
    const unsigned short* __restrict__ Ahi, const unsigned short* __restrict__ Alo,
    const unsigned short* __restrict__ Whi, const unsigned short* __restrict__ Wlo,
    const float* __restrict__ bias,
    float* __restrict__ outf,
    unsigned short* __restrict__ khi, unsigned short* __restrict__ klo,
    unsigned short* __restrict__ vt)
{
    __shared__ __align__(16) unsigned short As[128 * 64];
    __shared__ __align__(16) unsigned short Bs[128 * 64];
    const int K = KDIM;
    const int tid = threadIdx.x;
    const int wid = tid >> 6, lane = tid & 63;
    const int l15 = lane & 15, g = lane >> 4;
    const int m0 = blockIdx.y * 128, n0 = blockIdx.x * 128;
    const int wr = wid >> 1, wc = wid & 1;

    const f32x4 fzero = {0.f, 0.f, 0.f, 0.f};
    f32x4 acc[4][4];
#pragma unroll
    for (int i = 0; i < 4; ++i)
#pragma unroll
        for (int j = 0; j < 4; ++j) acc[i][j] = fzero;

    const unsigned short* APs[3] = {Ahi, Ahi, Alo};
    const unsigned short* WPs[3] = {Whi, Wlo, Whi};

    for (int p = 0; p < 3; ++p) {
        const unsigned short* Ap = APs[p] + (size_t)m0 * K;
        const unsigned short* Wp = WPs[p] + (size_t)n0 * K;
        for (int k0 = 0; k0 < K; k0 += 64) {
#pragma unroll
            for (int u = 0; u < 4; ++u) {
                int bo = wid * 4096 + u * 1024 + lane * 16;   // byte in 16KB tile
                int row = bo >> 7, col = (bo & 127) >> 1;
                int ub = (wid * 4096 + u * 1024) >> 1;         // wave-uniform elem base
                gload_lds16(Ap + (size_t)row * K + k0 + col, &As[ub]);
                gload_lds16(Wp + (size_t)row * K + k0 + col, &Bs[ub]);
            }
            __syncthreads();
#pragma unroll
            for (int kc = 0; kc < 2; ++kc) {
                bf16x8 af[4], bfr[4];
#pragma unroll
                for (int i = 0; i < 4; ++i)
                    af[i] = *(const bf16x8*)&As[(wr * 64 + i * 16 + l15) * 64 + kc * 32 + g * 8];
#pragma unroll
                for (int j = 0; j < 4; ++j)
                    bfr[j] = *(const bf16x8*)&Bs[(wc * 64 + j * 16 + l15) * 64 + kc * 32 + g * 8];
#pragma unroll
                for (int i = 0; i < 4; ++i)
#pragma unroll
                    for (int j = 0; j < 4; ++j)
                        acc[i][j] = __builtin_amdgcn_mfma_f32_16x16x32_bf16(af[i], bfr[j], acc[i][j], 0, 0, 0);
            }
            __syncthreads();
        }
    }

#pragma unroll
    for (int i = 0; i < 4; ++i) {
        int mbase = m0 + wr * 64 + i * 16 + g * 4;
#pragma unroll
        for (int j = 0; j < 4; ++j) {
            int n = n0 + wc * 64 + j * 16 + l15;
            float bv = bias[n];
            if (EPI == 2) {
#pragma unroll
                for (int r = 0; r < 4; ++r)
                    outf[(size_t)(mbase + r) * 1024 + n] = acc[i][j][r] + bv;
            } else {
                int which = n >> 10, rem = n & 1023, h = rem >> 6, d = rem & 63;
#pragma unroll
                for (int r = 0; r < 4; ++r) {
                    int mm = mbase + r;
                    int bb = mm >> 11, ll = mm & 2047;
                    size_t bh = (size_t)(bb * 16 + h);
                    float val = acc[i][j][r] + bv;
                    if (which == 0) {
                        outf[(bh * 2048 + ll) * 64 + d] = val;
                    } else if (which == 1) {
                        unsigned short hh = f2bf(val);
                        size_t idx = (bh * 2048 + ll) * 64 + d;
                        khi[idx] = hh;
                        klo[idx] = f2bf(val - bf2f(hh));
                    } else {
                        vt[(bh * 64 + d) * 2048 + ll] = f2bf(val);
                    }
                }
            }
        }
    }
}

// ---------------------------------------------------------------------------
// Flash attention, MFMA. 4 waves x 16 q-rows (QB=64), KV-tile 64.
// QK^T split-bf16 (3 passes); PV bf16.
// R4: T2 XOR-swizzle on K/V tiles (pre-swizzled gload_lds SOURCE + swizzled
// ds_read — rule #21 both-sides), Ps padded to stride 72 (VALU-written).
// ---------------------------------------------------------------------------
__global__ __launch_bounds__(256) void attn_mfma(
    const float* __restrict__ qws, const unsigned short* __restrict__ khi,
    const unsigned short* __restrict__ klo, const unsigned short* __restrict__ vt,
    const float* __restrict__ rel_emb,
    unsigned short* __restrict__ ohi, unsigned short* __restrict__ olo)
{
    __shared__ __align__(16) unsigned short Khi_s[64 * 64];
    __shared__ __align__(16) unsigned short Klo_s[64 * 64];
    __shared__ __align__(16) unsigned short Vt_s[64 * 64];
    __shared__ __align__(16) unsigned short Ps[64 * 72];   // +8 pad: 144B rows
    __shared__ float Rel[2 * MAX_REL + 1];

    // XCD-aware swizzle: 1024 WGs = 8 XCDs x 128; same (b,h) stays on one XCD.
    int flat = blockIdx.x + 32 * (blockIdx.y + 16 * blockIdx.z);
    int swz = (flat & 7) * 128 + (flat >> 3);
    int qb = swz & 31, h = (swz >> 5) & 15, b = swz >> 9;
    int q0 = qb * 64;

    const int tid = threadIdx.x;
    const int wid = tid >> 6, lane = tid & 63;
    const int l15 = lane & 15, g = lane >> 4;
    size_t bh = (size_t)(b * 16 + h);
    const float* qb_p = qws + bh * SEQ * 64;
    const unsigned short* kbh = khi + bh * SEQ * 64;
    const unsigned short* kbl = klo + bh * SEQ * 64;
    const unsigned short* vbt = vt + bh * 64 * SEQ;

    for (int i = tid; i < 2 * MAX_REL + 1; i += 256) Rel[i] = rel_emb[i * NHEAD + h];

    // Q fragments (hi/lo) in registers
    bf16x8 qhi[2], qlo[2];
    int qrow = q0 + wid * 16 + l15;
#pragma unroll
    for (int kc = 0; kc < 2; ++kc) {
        float4 f0 = *(const float4*)&qb_p[(size_t)qrow * 64 + kc * 32 + g * 8];
        float4 f1 = *(const float4*)&qb_p[(size_t)qrow * 64 + kc * 32 + g * 8 + 4];
        float ff[8] = {f0.x, f0.y, f0.z, f0.w, f1.x, f1.y, f1.z, f1.w};
#pragma unroll
        for (int j = 0; j < 8; ++j) {
            unsigned short hh = f2bf(ff[j]);
            qhi[kc][j] = (short)hh;
            qlo[kc][j] = (short)f2bf(ff[j] - bf2f(hh));
        }
    }

    const f32x4 fzero = {0.f, 0.f, 0.f, 0.f};
    f32x4 o[4];
    float m_run[4], l_run[4];
#pragma unroll
    for (int r = 0; r < 4; ++r) { m_run[r] = -1e30f; l_run[r] = 0.f; }
#pragma unroll
    for (int df = 0; df < 4; ++df) o[df] = fzero;

    for (int kt = 0; kt < SEQ / 64; ++kt) {
        int k0 = kt * 64;
        // stage K(hi,lo) and V^T tiles: LDS dest linear, global source chunk
        // XOR-swizzled (chunk ^= row&7) so LDS holds the swizzled layout.
#pragma unroll
        for (int u = 0; u < 2; ++u) {
            int bo = wid * 2048 + u * 1024 + lane * 16;
            int row = bo >> 7;
            int ch  = ((bo >> 4) & 7) ^ (row & 7);    // swizzled source chunk
            int col = ch * 8;                          // element col in tile
            int ub = (wid * 2048 + u * 1024) >> 1;
            gload_lds16(kbh + (size_t)(k0 + row) * 64 + col, &Khi_s[ub]);
            gload_lds16(kbl + (size_t)(k0 + row) * 64 + col, &Klo_s[ub]);
            gload_lds16(vbt + (size_t)row * SEQ + k0 + col, &Vt_s[ub]);
        }
        __syncthreads();

        // S = Q K^T (split, 3 passes); read-side swizzle matches staging
        f32x4 s[4];
#pragma unroll
        for (int cf = 0; cf < 4; ++cf) {
            s[cf] = fzero;
#pragma unroll
            for (int kc = 0; kc < 2; ++kc) {
                int swzc = (((kc * 4 + g) ^ (l15 & 7)) * 8);   // row&7 == l15&7
                bf16x8 kh = *(const bf16x8*)&Khi_s[(cf * 16 + l15) * 64 + swzc];
                bf16x8 kl = *(const bf16x8*)&Klo_s[(cf * 16 + l15) * 64 + swzc];
                s[cf] = __builtin_amdgcn_mfma_f32_16x16x32_bf16(qhi[kc], kh, s[cf], 0, 0, 0);
                s[cf] = __builtin_amdgcn_mfma_f32_16x16x32_bf16(qlo[kc], kh, s[cf], 0, 0, 0);
                s[cf] = __builtin_amdgcn_mfma_f32_16x16x32_bf16(qhi[kc], kl, s[cf], 0, 0, 0);
            }
        }

        // scale + rel-pos bias
        int qg = q0 + wid * 16 + g * 4;
#pragma unroll
        for (int cf = 0; cf < 4; ++cf) {
            int kg = k0 + cf * 16 + l15;
#pragma unroll
            for (int r = 0; r < 4; ++r) {
                int rel = kg - (qg + r);
                rel = rel < -MAX_REL ? -MAX_REL : (rel > MAX_REL ? MAX_REL : rel);
                s[cf][r] = fmaf(s[cf][r], 0.125f, Rel[rel + MAX_REL]);
            }
        }

        // online softmax: row = reg r, reduce over 16-lane key groups
#pragma unroll
        for (int r = 0; r < 4; ++r) {
            float mloc = fmaxf(fmaxf(s[0][r], s[1][r]), fmaxf(s[2][r], s[3][r]));
#pragma unroll
            for (int off = 1; off < 16; off <<= 1)
                mloc = fmaxf(mloc, __shfl_xor(mloc, off, 64));
            float mnew = fmaxf(m_run[r], mloc);
            float sc = __expf(m_run[r] - mnew);
            m_run[r] = mnew;
            float psum = 0.f;
#pragma unroll
            for (int cf = 0; cf < 4; ++cf) {
                float p = __expf(s[cf][r] - mnew);
                s[cf][r] = p;
                psum += p;
            }
#pragma unroll
            for (int off = 1; off < 16; off <<= 1)
                psum += __shfl_xor(psum, off, 64);
            l_run[r] = l_run[r] * sc + psum;
#pragma unroll
            for (int df = 0; df < 4; ++df) o[df][r] = o[df][r] * sc;  // row r only
        }

        // P -> LDS (bf16, padded stride 72), own-wave strip
#pragma unroll
        for (int cf = 0; cf < 4; ++cf)
#pragma unroll
            for (int r = 0; r < 4; ++r)
                Ps[(wid * 16 + g * 4 + r) * 72 + cf * 16 + l15] = f2bf(s[cf][r]);

        // O += P V
#pragma unroll
        for (int kc = 0; kc < 2; ++kc) {
            bf16x8 pa = *(const bf16x8*)&Ps[(wid * 16 + l15) * 72 + kc * 32 + g * 8];
#pragma unroll
            for (int df = 0; df < 4; ++df) {
                int swzc = (((kc * 4 + g) ^ (l15 & 7)) * 8);
                bf16x8 vb = *(const bf16x8*)&Vt_s[(df * 16 + l15) * 64 + swzc];
                o[df] = __builtin_amdgcn_mfma_f32_16x16x32_bf16(pa, vb, o[df], 0, 0, 0);
            }
        }
        __syncthreads();
    }

    // epilogue: normalize, split-write attn2 (hi, lo)
#pragma unroll
    for (int r = 0; r < 4; ++r) {
        float inv = 1.f / l_run[r];
        size_t row = (size_t)b * SEQ + q0 + wid * 16 + g * 4 + r;
#pragma unroll
        for (int df = 0; df < 4; ++df) {
            float val = o[df][r] * inv;
            unsigned short hh = f2bf(val);
            size_t idx = row * D_MODEL + h * 64 + df * 16 + l15;
            ohi[idx] = hh;
            olo[idx] = f2bf(val - bf2f(hh));
        }
    }
}

// ---------------------------------------------------------------------------
extern "C" void kernel_launch(void* const* d_in, const int* in_sizes, int n_in,
                              void* d_out, int out_size, void* d_ws, size_t ws_size,
                              hipStream_t stream)
{
    (void)in_sizes; (void)n_in; (void)out_size; (void)ws_size;
    const float* x       = (const float*)d_in[0];
    const float* qkv_w   = (const float*)d_in[1];
    const float* qkv_b   = (const float*)d_in[2];
    const float* out_w   = (const float*)d_in[3];
    const float* out_b   = (const float*)d_in[4];
    const float* rel_emb = (const float*)d_in[5];
    float* out = (float*)d_out;

    char* ws = (char*)d_ws;
    float*          qws  = (float*)(ws + 0);                    // 16 MB fp32 Q [b][h][l][d]
    unsigned short* khi  = (unsigned short*)(ws + 16777216);    // 8 MB
    unsigned short* klo  = (unsigned short*)(ws + 25165824);    // 8 MB
    unsigned short* vt   = (unsigned short*)(ws + 33554432);    // 8 MB [b][h][d][l]
    unsigned short* xhi  = (unsigned short*)(ws + 41943040);    // 8 MB (aliases attn2hi)
    unsigned short* xlo  = (unsigned short*)(ws + 50331648);    // 8 MB (aliases attn2lo)
    unsigned short* wqhi = (unsigned short*)(ws + 58720256);    // 6 MB
    unsigned short* wqlo = (unsigned short*)(ws + 65011712);    // 6 MB
    unsigned short* owhi = (unsigned short*)(ws + 71303168);    // 2 MB
    unsigned short* owlo = (unsigned short*)(ws + 73400320);    // 2 MB
    unsigned short* a2hi = xhi;   // attn2 split reuses x-split region
    unsigned short* a2lo = xlo;

    // 1) splits
    split_bf16<<<4096, 256, 0, stream>>>(x, xhi, xlo, 1048576);
    split_bf16<<<3072, 256, 0, stream>>>(qkv_w, wqhi, wqlo, 786432);
    split_bf16<<<1024, 256, 0, stream>>>(out_w, owhi, owlo, 262144);
    // 2) QKV projection (scatter epilogue)
    gemm_split<1><<<dim3(24, 32), 256, 0, stream>>>(xhi, xlo, wqhi, wqlo, qkv_b,
                                                    qws, khi, klo, vt);
    // 3) attention
    attn_mfma<<<dim3(32, 16, 2), 256, 0, stream>>>(qws, khi, klo, vt, rel_emb, a2hi, a2lo);
    // 4) out projection
    gemm_split<2><<<dim3(8, 32), 256, 0, stream>>>(a2hi, a2lo, owhi, owlo, out_b,
                                                   out, nullptr, nullptr, nullptr);
}